// Round 2
// baseline (1112.431 us; speedup 1.0000x reference)
//
#include <hip/hip_runtime.h>
#include <hip/hip_bf16.h>
#include <cstddef>

// Problem constants
constexpr int B_  = 2;
constexpr int T_  = 8;
constexpr int HW_ = 37;          // H == W == 37
constexpr int N_  = HW_ * HW_;   // 1369
constexpr int C_  = 384;
constexpr int NH_ = 8;
constexpr int MP_ = 8;
constexpr int HD_ = C_ / NH_;    // 48
constexpr int M_  = B_ * T_ * N_; // 21904

// ---------------------------------------------------------------------------
// Generic fp32 GEMM + bias: out[M,N] = A[M,K] @ W[K,N] + bias[N]
// Tiles: BM=64, BN=64, BK=16; 256 threads; 4x4 per thread.
// ---------------------------------------------------------------------------
#define BMg 64
#define BNg 64
#define BKg 16

__global__ __launch_bounds__(256)
void gemm_bias_kernel(const float* __restrict__ A, const float* __restrict__ W,
                      const float* __restrict__ bias, float* __restrict__ out,
                      int M, int N, int K) {
  __shared__ float As[BKg][BMg + 4];
  __shared__ float Bs[BKg][BNg + 4];
  const int tid = threadIdx.x;
  const int tx = tid & 15;
  const int ty = tid >> 4;
  const int block_m = blockIdx.x * BMg;
  const int block_n = blockIdx.y * BNg;
  float acc[4][4] = {};

  for (int k0 = 0; k0 < K; k0 += BKg) {
#pragma unroll
    for (int i = 0; i < 4; ++i) {
      int e = tid + i * 256;
      int m = e >> 4;
      int kk = e & 15;
      int gm = block_m + m;
      As[kk][m] = (gm < M) ? A[(size_t)gm * K + (k0 + kk)] : 0.f;
    }
#pragma unroll
    for (int i = 0; i < 4; ++i) {
      int e = tid + i * 256;
      int kk = e >> 6;
      int nn = e & 63;
      Bs[kk][nn] = W[(size_t)(k0 + kk) * N + block_n + nn];
    }
    __syncthreads();
#pragma unroll
    for (int kk = 0; kk < BKg; ++kk) {
      float4 a4 = *(const float4*)&As[kk][ty * 4];
      float4 b4 = *(const float4*)&Bs[kk][tx * 4];
      float a[4] = {a4.x, a4.y, a4.z, a4.w};
      float b[4] = {b4.x, b4.y, b4.z, b4.w};
#pragma unroll
      for (int i = 0; i < 4; ++i)
#pragma unroll
        for (int j = 0; j < 4; ++j)
          acc[i][j] += a[i] * b[j];
    }
    __syncthreads();
  }

#pragma unroll
  for (int i = 0; i < 4; ++i) {
    int gm = block_m + ty * 4 + i;
    if (gm >= M) continue;
#pragma unroll
    for (int j = 0; j < 4; ++j) {
      int gn = block_n + tx * 4 + j;
      out[(size_t)gm * N + gn] = acc[i][j] + bias[gn];
    }
  }
}

// ---------------------------------------------------------------------------
// Deformable attention core — zero LDS, zero barriers.
// Lane role: p = lane>>3 (point), k = lane&7 (channel group d = 6k..6k+5).
// Each wave handles 2 heads of one (b,t,n). Per (head, r):
//   gather 4 bilinear taps (3x float2 each) -> s[6] in registers,
//   logit = k-group shuffle-reduce of q.s, softmax over p via xor(8,16,32),
//   oa[j] += attn * s[j]  (per-lane p-partials; p-reduced once per head).
// ---------------------------------------------------------------------------
__global__ __launch_bounds__(256)
void attend_kernel(const float* __restrict__ f, const float* __restrict__ Q,
                   const float* __restrict__ OFF, float* __restrict__ O1) {
  const int blk = blockIdx.x;        // (b*T + t)*N + n
  const int n   = blk % N_;
  const int bt  = blk / N_;
  const int t   = bt % T_;
  const int b   = bt / T_;
  const int w    = threadIdx.x >> 6;
  const int lane = threadIdx.x & 63;
  const int p = lane >> 3;
  const int k = lane & 7;
  const size_t row = (size_t)bt * N_ + n;
  const float cy = (float)(n / HW_);
  const float cx = (float)(n % HW_);
  const float* fb0 = f + (size_t)b * T_ * N_ * C_;   // batch base

  for (int hi = 0; hi < 2; ++hi) {
    const int h = w * 2 + hi;

    // q fragment for my channel slice (8-lane groups read same 192B -> broadcast)
    const float* qp = Q + row * C_ + h * HD_ + 6 * k;
    float q0 = qp[0], q1 = qp[1], q2 = qp[2], q3 = qp[3], q4 = qp[4], q5 = qp[5];

    // bilinear taps for my point p (computed redundantly per k-lane; cheap)
    const float* op = OFF + row * (NH_ * MP_ * 2) + h * (MP_ * 2) + p * 2;
    float y = cy + op[0];
    float x = cx + op[1];
    float y0f = floorf(y), x0f = floorf(x);
    float wy = y - y0f, wx = x - x0f;
    int y0 = (int)y0f, x0 = (int)x0f;
    int y1 = y0 + 1, x1 = x0 + 1;
    float vy0 = (y0 >= 0 && y0 < HW_) ? 1.f : 0.f;
    float vy1 = (y1 >= 0 && y1 < HW_) ? 1.f : 0.f;
    float vx0 = (x0 >= 0 && x0 < HW_) ? 1.f : 0.f;
    float vx1 = (x1 >= 0 && x1 < HW_) ? 1.f : 0.f;
    int cy0 = min(max(y0, 0), HW_ - 1), cy1 = min(max(y1, 0), HW_ - 1);
    int cx0 = min(max(x0, 0), HW_ - 1), cx1 = min(max(x1, 0), HW_ - 1);
    // element offsets within a frame (include channel base), 32-bit safe
    const int chb = h * HD_ + 6 * k;
    int off0 = (cy0 * HW_ + cx0) * C_ + chb;
    int off1 = (cy0 * HW_ + cx1) * C_ + chb;
    int off2 = (cy1 * HW_ + cx0) * C_ + chb;
    int off3 = (cy1 * HW_ + cx1) * C_ + chb;
    float tw0 = (1.f - wy) * (1.f - wx) * vy0 * vx0;
    float tw1 = (1.f - wy) * wx * vy0 * vx1;
    float tw2 = wy * (1.f - wx) * vy1 * vx0;
    float tw3 = wy * wx * vy1 * vx1;

    float oa0 = 0, oa1 = 0, oa2 = 0, oa3 = 0, oa4 = 0, oa5 = 0;

#pragma unroll 2
    for (int r = 0; r < T_; ++r) {
      const float* fr = fb0 + (size_t)r * (N_ * C_);
      const float* p0 = fr + off0;
      const float* p1 = fr + off1;
      const float* p2 = fr + off2;
      const float* p3 = fr + off3;
      float2 a0 = *(const float2*)(p0 + 0), a1 = *(const float2*)(p0 + 2), a2 = *(const float2*)(p0 + 4);
      float2 b0 = *(const float2*)(p1 + 0), b1 = *(const float2*)(p1 + 2), b2 = *(const float2*)(p1 + 4);
      float2 c0 = *(const float2*)(p2 + 0), c1 = *(const float2*)(p2 + 2), c2 = *(const float2*)(p2 + 4);
      float2 d0 = *(const float2*)(p3 + 0), d1 = *(const float2*)(p3 + 2), d2 = *(const float2*)(p3 + 4);
      float s0 = tw0 * a0.x + tw1 * b0.x + tw2 * c0.x + tw3 * d0.x;
      float s1 = tw0 * a0.y + tw1 * b0.y + tw2 * c0.y + tw3 * d0.y;
      float s2 = tw0 * a1.x + tw1 * b1.x + tw2 * c1.x + tw3 * d1.x;
      float s3 = tw0 * a1.y + tw1 * b1.y + tw2 * c1.y + tw3 * d1.y;
      float s4 = tw0 * a2.x + tw1 * b2.x + tw2 * c2.x + tw3 * d2.x;
      float s5 = tw0 * a2.y + tw1 * b2.y + tw2 * c2.y + tw3 * d2.y;

      // logit: k-group reduce (lanes differing in bits 0..2 share p)
      float lg = q0 * s0 + q1 * s1 + q2 * s2 + q3 * s3 + q4 * s4 + q5 * s5;
      lg += __shfl_xor(lg, 1);
      lg += __shfl_xor(lg, 2);
      lg += __shfl_xor(lg, 4);
      lg *= 0.144337567297406441f;   // 1/sqrt(48)

      int dd = t - r; dd = dd < 0 ? -dd : dd;
      int npts = (56 - 8 * dd) / 7; npts = npts < 1 ? 1 : npts;
      if (p >= npts) lg = -1e30f;

      // softmax over p (lanes differing in bits 3..5 share k)
      float m = lg;
      m = fmaxf(m, __shfl_xor(m, 8));
      m = fmaxf(m, __shfl_xor(m, 16));
      m = fmaxf(m, __shfl_xor(m, 32));
      float e = __expf(lg - m);
      float ssum = e;
      ssum += __shfl_xor(ssum, 8);
      ssum += __shfl_xor(ssum, 16);
      ssum += __shfl_xor(ssum, 32);
      float attn = e / ssum * 0.125f;   // fold 1/T mean

      oa0 += attn * s0; oa1 += attn * s1; oa2 += attn * s2;
      oa3 += attn * s3; oa4 += attn * s4; oa5 += attn * s5;
    }

    // p-reduction (once per head)
    oa0 += __shfl_xor(oa0, 8); oa0 += __shfl_xor(oa0, 16); oa0 += __shfl_xor(oa0, 32);
    oa1 += __shfl_xor(oa1, 8); oa1 += __shfl_xor(oa1, 16); oa1 += __shfl_xor(oa1, 32);
    oa2 += __shfl_xor(oa2, 8); oa2 += __shfl_xor(oa2, 16); oa2 += __shfl_xor(oa2, 32);
    oa3 += __shfl_xor(oa3, 8); oa3 += __shfl_xor(oa3, 16); oa3 += __shfl_xor(oa3, 32);
    oa4 += __shfl_xor(oa4, 8); oa4 += __shfl_xor(oa4, 16); oa4 += __shfl_xor(oa4, 32);
    oa5 += __shfl_xor(oa5, 8); oa5 += __shfl_xor(oa5, 16); oa5 += __shfl_xor(oa5, 32);

    if (p == 0) {
      float* outp = O1 + row * C_ + h * HD_ + 6 * k;
      float2 v0 = {oa0, oa1}, v1 = {oa2, oa3}, v2 = {oa4, oa5};
      *(float2*)(outp + 0) = v0;
      *(float2*)(outp + 2) = v1;
      *(float2*)(outp + 4) = v2;
    }
  }
}

// ---------------------------------------------------------------------------
extern "C" void kernel_launch(void* const* d_in, const int* in_sizes, int n_in,
                              void* d_out, int out_size, void* d_ws, size_t ws_size,
                              hipStream_t stream) {
  const float* f    = (const float*)d_in[0];
  const float* Wq   = (const float*)d_in[1];
  const float* bq   = (const float*)d_in[2];
  const float* Woff = (const float*)d_in[3];
  const float* boff = (const float*)d_in[4];
  const float* Wout = (const float*)d_in[5];
  const float* bout = (const float*)d_in[6];
  float* outp = (float*)d_out;

  float* Qbuf = (float*)d_ws;                          // [M, 384]
  float* OFFb = Qbuf + (size_t)M_ * C_;                // [M, 128]
  float* O1   = OFFb + (size_t)M_ * (NH_ * MP_ * 2);   // [M, 384]

  dim3 blk(256);
  dim3 gq((M_ + BMg - 1) / BMg, C_ / BNg);             // 343 x 6
  gemm_bias_kernel<<<gq, blk, 0, stream>>>(f, Wq, bq, Qbuf, M_, C_, C_);

  dim3 go((M_ + BMg - 1) / BMg, (NH_ * MP_ * 2) / BNg); // 343 x 2
  gemm_bias_kernel<<<go, blk, 0, stream>>>(f, Woff, boff, OFFb, M_, NH_ * MP_ * 2, C_);

  attend_kernel<<<dim3(M_), blk, 0, stream>>>(f, Qbuf, OFFb, O1);

  gemm_bias_kernel<<<gq, blk, 0, stream>>>(O1, Wout, bout, outp, M_, C_, C_);
}

// Round 3
// 621.604 us; speedup vs baseline: 1.7896x; 1.7896x over previous
//
#include <hip/hip_runtime.h>
#include <hip/hip_bf16.h>
#include <cstddef>

// Problem constants
constexpr int B_  = 2;
constexpr int T_  = 8;
constexpr int HW_ = 37;          // H == W == 37
constexpr int N_  = HW_ * HW_;   // 1369
constexpr int C_  = 384;
constexpr int NH_ = 8;
constexpr int MP_ = 8;
constexpr int HD_ = C_ / NH_;    // 48
constexpr int M_  = B_ * T_ * N_; // 21904

// ---------------------------------------------------------------------------
// Generic fp32 GEMM + bias: out[M,N] = A[M,K] @ W[K,N] + bias[N]
// ---------------------------------------------------------------------------
#define BMg 64
#define BNg 64
#define BKg 16

__global__ __launch_bounds__(256)
void gemm_bias_kernel(const float* __restrict__ A, const float* __restrict__ W,
                      const float* __restrict__ bias, float* __restrict__ out,
                      int M, int N, int K) {
  __shared__ float As[BKg][BMg + 4];
  __shared__ float Bs[BKg][BNg + 4];
  const int tid = threadIdx.x;
  const int tx = tid & 15;
  const int ty = tid >> 4;
  const int block_m = blockIdx.x * BMg;
  const int block_n = blockIdx.y * BNg;
  float acc[4][4] = {};

  for (int k0 = 0; k0 < K; k0 += BKg) {
#pragma unroll
    for (int i = 0; i < 4; ++i) {
      int e = tid + i * 256;
      int m = e >> 4;
      int kk = e & 15;
      int gm = block_m + m;
      As[kk][m] = (gm < M) ? A[(size_t)gm * K + (k0 + kk)] : 0.f;
    }
#pragma unroll
    for (int i = 0; i < 4; ++i) {
      int e = tid + i * 256;
      int kk = e >> 6;
      int nn = e & 63;
      Bs[kk][nn] = W[(size_t)(k0 + kk) * N + block_n + nn];
    }
    __syncthreads();
#pragma unroll
    for (int kk = 0; kk < BKg; ++kk) {
      float4 a4 = *(const float4*)&As[kk][ty * 4];
      float4 b4 = *(const float4*)&Bs[kk][tx * 4];
      float a[4] = {a4.x, a4.y, a4.z, a4.w};
      float b[4] = {b4.x, b4.y, b4.z, b4.w};
#pragma unroll
      for (int i = 0; i < 4; ++i)
#pragma unroll
        for (int j = 0; j < 4; ++j)
          acc[i][j] += a[i] * b[j];
    }
    __syncthreads();
  }

#pragma unroll
  for (int i = 0; i < 4; ++i) {
    int gm = block_m + ty * 4 + i;
    if (gm >= M) continue;
#pragma unroll
    for (int j = 0; j < 4; ++j) {
      int gn = block_n + tx * 4 + j;
      out[(size_t)gm * N + gn] = acc[i][j] + bias[gn];
    }
  }
}

// ---------------------------------------------------------------------------
// Transpose + cast: ft[b][n][t][c] (bf16) = f[b][t][n][c] (fp32).
// Puts the T axis adjacent to C so one sampling location's 8 ref-frame reads
// land in one contiguous 6KB chunk; halves gather bytes.
// ---------------------------------------------------------------------------
__global__ __launch_bounds__(256)
void transpose_cast_kernel(const float* __restrict__ f,
                           __hip_bfloat16* __restrict__ ft) {
  const int bn = blockIdx.x;          // b*N + n
  const int n = bn % N_;
  const int b = bn / N_;
  const size_t dst_base = (size_t)bn * (T_ * C_);
#pragma unroll
  for (int i = 0; i < 12; ++i) {      // 12*256 = 3072 = T*C
    int idx = i * 256 + threadIdx.x;  // t*C + c
    int t = idx / C_;
    int c = idx - t * C_;
    float v = f[((size_t)(b * T_ + t) * N_ + n) * C_ + c];
    ft[dst_base + idx] = __float2bfloat16(v);
  }
}

// ---------------------------------------------------------------------------
// Deformable attention core — zero LDS/barriers, bf16 transposed features.
// Lane role: p = lane>>3 (point), k = lane&7 (channel slice d = 6k..6k+5).
// Each wave handles 2 heads of one (b,t,n).
// ---------------------------------------------------------------------------
#define LOF(u) __uint_as_float((u) << 16)
#define HIF(u) __uint_as_float((u) & 0xffff0000u)

__global__ __launch_bounds__(256)
void attend_kernel(const __hip_bfloat16* __restrict__ ft,
                   const float* __restrict__ Q,
                   const float* __restrict__ OFF, float* __restrict__ O1) {
  const int blk = blockIdx.x;        // (b*T + t)*N + n
  const int n   = blk % N_;
  const int bt  = blk / N_;
  const int t   = bt % T_;
  const int b   = bt / T_;
  const int w    = threadIdx.x >> 6;
  const int lane = threadIdx.x & 63;
  const int p = lane >> 3;
  const int k = lane & 7;
  const size_t row = (size_t)bt * N_ + n;
  const float cy = (float)(n / HW_);
  const float cx = (float)(n % HW_);

  for (int hi = 0; hi < 2; ++hi) {
    const int h = w * 2 + hi;

    // q fragment for my channel slice
    const float* qp = Q + row * C_ + h * HD_ + 6 * k;
    float q0 = qp[0], q1 = qp[1], q2 = qp[2], q3 = qp[3], q4 = qp[4], q5 = qp[5];

    // bilinear taps for my point p
    const float* op = OFF + row * (NH_ * MP_ * 2) + h * (MP_ * 2) + p * 2;
    float y = cy + op[0];
    float x = cx + op[1];
    float y0f = floorf(y), x0f = floorf(x);
    float wy = y - y0f, wx = x - x0f;
    int y0 = (int)y0f, x0 = (int)x0f;
    int y1 = y0 + 1, x1 = x0 + 1;
    float vy0 = (y0 >= 0 && y0 < HW_) ? 1.f : 0.f;
    float vy1 = (y1 >= 0 && y1 < HW_) ? 1.f : 0.f;
    float vx0 = (x0 >= 0 && x0 < HW_) ? 1.f : 0.f;
    float vx1 = (x1 >= 0 && x1 < HW_) ? 1.f : 0.f;
    int cy0 = min(max(y0, 0), HW_ - 1), cy1 = min(max(y1, 0), HW_ - 1);
    int cx0 = min(max(x0, 0), HW_ - 1), cx1 = min(max(x1, 0), HW_ - 1);
    float tw0 = (1.f - wy) * (1.f - wx) * vy0 * vx0;
    float tw1 = (1.f - wy) * wx * vy0 * vx1;
    float tw2 = wy * (1.f - wx) * vy1 * vx0;
    float tw3 = wy * wx * vy1 * vx1;

    // element-offset bases into ft for each tap (b,n_tap fixed; +r*C per ref)
    const int chb = h * HD_ + 6 * k;
    const int bnb = b * N_;
    int base0 = ((bnb + cy0 * HW_ + cx0) * T_) * C_ + chb;
    int base1 = ((bnb + cy0 * HW_ + cx1) * T_) * C_ + chb;
    int base2 = ((bnb + cy1 * HW_ + cx0) * T_) * C_ + chb;
    int base3 = ((bnb + cy1 * HW_ + cx1) * T_) * C_ + chb;

    float oa0 = 0, oa1 = 0, oa2 = 0, oa3 = 0, oa4 = 0, oa5 = 0;

#pragma unroll 2
    for (int r = 0; r < T_; ++r) {
      const int roff = r * C_;
      const unsigned* ta = (const unsigned*)(ft + base0 + roff);
      const unsigned* tb = (const unsigned*)(ft + base1 + roff);
      const unsigned* tc = (const unsigned*)(ft + base2 + roff);
      const unsigned* td = (const unsigned*)(ft + base3 + roff);
      unsigned ua0 = ta[0], ua1 = ta[1], ua2 = ta[2];
      unsigned ub0 = tb[0], ub1 = tb[1], ub2 = tb[2];
      unsigned uc0 = tc[0], uc1 = tc[1], uc2 = tc[2];
      unsigned ud0 = td[0], ud1 = td[1], ud2 = td[2];

      float s0 = tw0 * LOF(ua0) + tw1 * LOF(ub0) + tw2 * LOF(uc0) + tw3 * LOF(ud0);
      float s1 = tw0 * HIF(ua0) + tw1 * HIF(ub0) + tw2 * HIF(uc0) + tw3 * HIF(ud0);
      float s2 = tw0 * LOF(ua1) + tw1 * LOF(ub1) + tw2 * LOF(uc1) + tw3 * LOF(ud1);
      float s3 = tw0 * HIF(ua1) + tw1 * HIF(ub1) + tw2 * HIF(uc1) + tw3 * HIF(ud1);
      float s4 = tw0 * LOF(ua2) + tw1 * LOF(ub2) + tw2 * LOF(uc2) + tw3 * LOF(ud2);
      float s5 = tw0 * HIF(ua2) + tw1 * HIF(ub2) + tw2 * HIF(uc2) + tw3 * HIF(ud2);

      // logit: k-group reduce (lanes differing in bits 0..2 share p)
      float lg = q0 * s0 + q1 * s1 + q2 * s2 + q3 * s3 + q4 * s4 + q5 * s5;
      lg += __shfl_xor(lg, 1);
      lg += __shfl_xor(lg, 2);
      lg += __shfl_xor(lg, 4);
      lg *= 0.144337567297406441f;   // 1/sqrt(48)

      int dd = t - r; dd = dd < 0 ? -dd : dd;
      int npts = (56 - 8 * dd) / 7; npts = npts < 1 ? 1 : npts;
      if (p >= npts) lg = -1e30f;

      // softmax over p (lanes differing in bits 3..5 share k)
      float m = lg;
      m = fmaxf(m, __shfl_xor(m, 8));
      m = fmaxf(m, __shfl_xor(m, 16));
      m = fmaxf(m, __shfl_xor(m, 32));
      float e = __expf(lg - m);
      float ssum = e;
      ssum += __shfl_xor(ssum, 8);
      ssum += __shfl_xor(ssum, 16);
      ssum += __shfl_xor(ssum, 32);
      float attn = e / ssum * 0.125f;   // fold 1/T mean

      oa0 += attn * s0; oa1 += attn * s1; oa2 += attn * s2;
      oa3 += attn * s3; oa4 += attn * s4; oa5 += attn * s5;
    }

    // p-reduction (once per head)
    oa0 += __shfl_xor(oa0, 8); oa0 += __shfl_xor(oa0, 16); oa0 += __shfl_xor(oa0, 32);
    oa1 += __shfl_xor(oa1, 8); oa1 += __shfl_xor(oa1, 16); oa1 += __shfl_xor(oa1, 32);
    oa2 += __shfl_xor(oa2, 8); oa2 += __shfl_xor(oa2, 16); oa2 += __shfl_xor(oa2, 32);
    oa3 += __shfl_xor(oa3, 8); oa3 += __shfl_xor(oa3, 16); oa3 += __shfl_xor(oa3, 32);
    oa4 += __shfl_xor(oa4, 8); oa4 += __shfl_xor(oa4, 16); oa4 += __shfl_xor(oa4, 32);
    oa5 += __shfl_xor(oa5, 8); oa5 += __shfl_xor(oa5, 16); oa5 += __shfl_xor(oa5, 32);

    if (p == 0) {
      float* outp = O1 + row * C_ + h * HD_ + 6 * k;
      float2 v0 = {oa0, oa1}, v1 = {oa2, oa3}, v2 = {oa4, oa5};
      *(float2*)(outp + 0) = v0;
      *(float2*)(outp + 2) = v1;
      *(float2*)(outp + 4) = v2;
    }
  }
}

// ---------------------------------------------------------------------------
extern "C" void kernel_launch(void* const* d_in, const int* in_sizes, int n_in,
                              void* d_out, int out_size, void* d_ws, size_t ws_size,
                              hipStream_t stream) {
  const float* f    = (const float*)d_in[0];
  const float* Wq   = (const float*)d_in[1];
  const float* bq   = (const float*)d_in[2];
  const float* Woff = (const float*)d_in[3];
  const float* boff = (const float*)d_in[4];
  const float* Wout = (const float*)d_in[5];
  const float* bout = (const float*)d_in[6];
  float* outp = (float*)d_out;

  float* Qbuf = (float*)d_ws;                          // [M, 384] fp32
  float* OFFb = Qbuf + (size_t)M_ * C_;                // [M, 128] fp32
  float* O1   = OFFb + (size_t)M_ * (NH_ * MP_ * 2);   // [M, 384] fp32
  __hip_bfloat16* ft = (__hip_bfloat16*)(O1 + (size_t)M_ * C_); // [B,N,T,C] bf16

  dim3 blk(256);
  dim3 gq((M_ + BMg - 1) / BMg, C_ / BNg);             // 343 x 6
  gemm_bias_kernel<<<gq, blk, 0, stream>>>(f, Wq, bq, Qbuf, M_, C_, C_);

  dim3 go((M_ + BMg - 1) / BMg, (NH_ * MP_ * 2) / BNg); // 343 x 2
  gemm_bias_kernel<<<go, blk, 0, stream>>>(f, Woff, boff, OFFb, M_, NH_ * MP_ * 2, C_);

  transpose_cast_kernel<<<dim3(B_ * N_), blk, 0, stream>>>(f, ft);

  attend_kernel<<<dim3(M_), blk, 0, stream>>>(ft, Qbuf, OFFb, O1);

  gemm_bias_kernel<<<gq, blk, 0, stream>>>(O1, Wout, bout, outp, M_, C_, C_);
}

// Round 4
// 384.426 us; speedup vs baseline: 2.8937x; 1.6170x over previous
//
#include <hip/hip_runtime.h>
#include <hip/hip_bf16.h>
#include <cstddef>

// Problem constants
constexpr int B_  = 2;
constexpr int T_  = 8;
constexpr int HW_ = 37;          // H == W == 37
constexpr int N_  = HW_ * HW_;   // 1369
constexpr int C_  = 384;
constexpr int NH_ = 8;
constexpr int MP_ = 8;
constexpr int HD_ = C_ / NH_;    // 48
constexpr int M_  = B_ * T_ * N_; // 21904

typedef short bf16x8 __attribute__((ext_vector_type(8)));
typedef float f32x4 __attribute__((ext_vector_type(4)));

static __device__ __forceinline__ unsigned short bf16_bits(float v) {
  __hip_bfloat16 b = __float2bfloat16(v);
  return *reinterpret_cast<unsigned short*>(&b);
}

// ---------------------------------------------------------------------------
// cast f (fp32, [M*C]) -> A16 (bf16, same layout). 4 elems/thread.
// ---------------------------------------------------------------------------
__global__ __launch_bounds__(256)
void cast_a_kernel(const float* __restrict__ f, __hip_bfloat16* __restrict__ A16) {
  int i = blockIdx.x * 256 + threadIdx.x;       // grid sized exactly: M*C/4 threads
  float4 v = ((const float4*)f)[i];
  ushort4 o;
  o.x = bf16_bits(v.x); o.y = bf16_bits(v.y);
  o.z = bf16_bits(v.z); o.w = bf16_bits(v.w);
  ((ushort4*)A16)[i] = o;
}

// ---------------------------------------------------------------------------
// Pre-transpose weights to [N][K] bf16.
// Wt [512][384]: rows 0..383 = Wq cols, rows 384..511 = Woff cols.
// Wot [384][384]: Wout cols.
// ---------------------------------------------------------------------------
__global__ __launch_bounds__(256)
void prep_w_kernel(const float* __restrict__ Wq, const float* __restrict__ Woff,
                   const float* __restrict__ Wout,
                   __hip_bfloat16* __restrict__ Wt, __hip_bfloat16* __restrict__ Wot) {
  int nrow = blockIdx.x;           // 0..895
  if (nrow < 512) {
    const float* src; int col, ld;
    if (nrow < 384) { src = Wq; col = nrow; ld = 384; }
    else            { src = Woff; col = nrow - 384; ld = 128; }
    for (int k = threadIdx.x; k < 384; k += 256)
      Wt[(size_t)nrow * 384 + k] = __float2bfloat16(src[(size_t)k * ld + col]);
  } else {
    int col = nrow - 512;
    for (int k = threadIdx.x; k < 384; k += 256)
      Wot[(size_t)col * 384 + k] = __float2bfloat16(Wout[(size_t)k * 384 + col]);
  }
}

// ---------------------------------------------------------------------------
// Transpose + cast: ft[b][n][t][c] (bf16) = f[b][t][n][c] (fp32).
// ---------------------------------------------------------------------------
__global__ __launch_bounds__(256)
void transpose_cast_kernel(const float* __restrict__ f,
                           __hip_bfloat16* __restrict__ ft) {
  const int bn = blockIdx.x;          // b*N + n
  const int n = bn % N_;
  const int b = bn / N_;
  const size_t dst_base = (size_t)bn * (T_ * C_);
#pragma unroll
  for (int i = 0; i < 12; ++i) {      // 12*256 = 3072 = T*C
    int idx = i * 256 + threadIdx.x;  // t*C + c
    int t = idx / C_;
    int c = idx - t * C_;
    float v = f[((size_t)(b * T_ + t) * N_ + n) * C_ + c];
    ft[dst_base + idx] = __float2bfloat16(v);
  }
}

// ---------------------------------------------------------------------------
// bf16 MFMA GEMM: out[M,N] = A[M,384] @ Wt[N,384]^T + bias.
// BM=128, BN=128, BK=32; 256 threads = 4 waves (2x2), wave = 64x64 (4x4 frags).
// split=1: N=512, cols<384 -> out0[M,384]+b0, cols>=384 -> out1[M,128]+b1.
// split=0: N from grid, out0[M,384]+b0.
// ---------------------------------------------------------------------------
__global__ __launch_bounds__(256)
void mfma_gemm_kernel(const __hip_bfloat16* __restrict__ A,
                      const __hip_bfloat16* __restrict__ Wt,
                      const float* __restrict__ b0, const float* __restrict__ b1,
                      float* __restrict__ out0, float* __restrict__ out1,
                      int split) {
  __shared__ __hip_bfloat16 As[128][40];   // stride 80B: 16B-aligned rows, ~2-way banks
  __shared__ __hip_bfloat16 Bs[128][40];
  const int m0 = blockIdx.x * 128;
  const int n0 = blockIdx.y * 128;
  const int tid = threadIdx.x;
  const int wv = tid >> 6, lane = tid & 63;
  const int wr = wv >> 1, wc = wv & 1;
  const int lr = lane & 15, kg = lane >> 4;

  f32x4 acc[4][4] = {};

  for (int k0 = 0; k0 < 384; k0 += 32) {
#pragma unroll
    for (int u = 0; u < 2; ++u) {
      int c = tid + u * 256;            // 0..511
      int row = c >> 2;
      int off = (c & 3) * 8;            // element offset (16B chunks)
      int gm = m0 + row;
      uint4 va = make_uint4(0u, 0u, 0u, 0u);
      if (gm < M_) va = *(const uint4*)(A + (size_t)gm * 384 + k0 + off);
      *(uint4*)&As[row][off] = va;
      uint4 vb = *(const uint4*)(Wt + (size_t)(n0 + row) * 384 + k0 + off);
      *(uint4*)&Bs[row][off] = vb;
    }
    __syncthreads();

    bf16x8 af[4], bfr[4];
#pragma unroll
    for (int i = 0; i < 4; ++i)
      af[i] = *(const bf16x8*)&As[wr * 64 + i * 16 + lr][kg * 8];
#pragma unroll
    for (int i = 0; i < 4; ++i)
      bfr[i] = *(const bf16x8*)&Bs[wc * 64 + i * 16 + lr][kg * 8];

#pragma unroll
    for (int mi = 0; mi < 4; ++mi)
#pragma unroll
      for (int ni = 0; ni < 4; ++ni)
        acc[mi][ni] = __builtin_amdgcn_mfma_f32_16x16x32_bf16(
            af[mi], bfr[ni], acc[mi][ni], 0, 0, 0);
    __syncthreads();
  }

  // epilogue: D elem (m = (lane>>4)*4 + j, n = lane&15) per 16x16 frag
  const int mrow = (lane >> 4) * 4;
#pragma unroll
  for (int mi = 0; mi < 4; ++mi) {
#pragma unroll
    for (int ni = 0; ni < 4; ++ni) {
#pragma unroll
      for (int j = 0; j < 4; ++j) {
        int gm = m0 + wr * 64 + mi * 16 + mrow + j;
        int gn = n0 + wc * 64 + ni * 16 + lr;
        if (gm >= M_) continue;
        float v = acc[mi][ni][j];
        if (!split) {
          out0[(size_t)gm * 384 + gn] = v + b0[gn];
        } else {
          if (gn < 384) out0[(size_t)gm * 384 + gn] = v + b0[gn];
          else          out1[(size_t)gm * 128 + (gn - 384)] = v + b1[gn - 384];
        }
      }
    }
  }
}

// ---------------------------------------------------------------------------
// Deformable attention core — block = (b,n), all T query frames inside.
// Lane role: p = lane>>3 (point), k = lane&7 (channel slice d = 6k..6k+5).
// Each wave handles 2 heads. Output O1 written in bf16 (feeds out-GEMM).
// Bijective chunked XCD swizzle: each XCD sweeps a contiguous (b,n)-range.
// ---------------------------------------------------------------------------
#define LOF(u) __uint_as_float((u) << 16)
#define HIF(u) __uint_as_float((u) & 0xffff0000u)

__global__ __launch_bounds__(256)
void attend_kernel(const __hip_bfloat16* __restrict__ ft,
                   const float* __restrict__ Q,
                   const float* __restrict__ OFF,
                   __hip_bfloat16* __restrict__ O1) {
  // chunked XCD swizzle over grid of B*N = 2738 blocks
  const int grid = B_ * N_;
  const int q8 = grid / 8, r8 = grid % 8;
  int c = blockIdx.x & 7, j = blockIdx.x >> 3;
  int bn = (c < r8) ? c * (q8 + 1) + j : r8 * (q8 + 1) + (c - r8) * q8 + j;

  const int n = bn % N_;
  const int b = bn / N_;
  const int w    = threadIdx.x >> 6;
  const int lane = threadIdx.x & 63;
  const int p = lane >> 3;
  const int k = lane & 7;
  const float cy = (float)(n / HW_);
  const float cx = (float)(n % HW_);
  const int bnb = b * N_;

  for (int t = 0; t < T_; ++t) {
    const size_t row = (size_t)(b * T_ + t) * N_ + n;

    for (int hi = 0; hi < 2; ++hi) {
      const int h = w * 2 + hi;

      // q fragment for my channel slice
      const float* qp = Q + row * C_ + h * HD_ + 6 * k;
      float q0 = qp[0], q1 = qp[1], q2 = qp[2], q3 = qp[3], q4 = qp[4], q5 = qp[5];

      // bilinear taps for my point p
      const float* op = OFF + row * (NH_ * MP_ * 2) + h * (MP_ * 2) + p * 2;
      float y = cy + op[0];
      float x = cx + op[1];
      float y0f = floorf(y), x0f = floorf(x);
      float wy = y - y0f, wx = x - x0f;
      int y0 = (int)y0f, x0 = (int)x0f;
      int y1 = y0 + 1, x1 = x0 + 1;
      float vy0 = (y0 >= 0 && y0 < HW_) ? 1.f : 0.f;
      float vy1 = (y1 >= 0 && y1 < HW_) ? 1.f : 0.f;
      float vx0 = (x0 >= 0 && x0 < HW_) ? 1.f : 0.f;
      float vx1 = (x1 >= 0 && x1 < HW_) ? 1.f : 0.f;
      int cy0 = min(max(y0, 0), HW_ - 1), cy1 = min(max(y1, 0), HW_ - 1);
      int cx0 = min(max(x0, 0), HW_ - 1), cx1 = min(max(x1, 0), HW_ - 1);
      float tw0 = (1.f - wy) * (1.f - wx) * vy0 * vx0;
      float tw1 = (1.f - wy) * wx * vy0 * vx1;
      float tw2 = wy * (1.f - wx) * vy1 * vx0;
      float tw3 = wy * wx * vy1 * vx1;

      const int chb = h * HD_ + 6 * k;
      int base0 = ((bnb + cy0 * HW_ + cx0) * T_) * C_ + chb;
      int base1 = ((bnb + cy0 * HW_ + cx1) * T_) * C_ + chb;
      int base2 = ((bnb + cy1 * HW_ + cx0) * T_) * C_ + chb;
      int base3 = ((bnb + cy1 * HW_ + cx1) * T_) * C_ + chb;

      float oa0 = 0, oa1 = 0, oa2 = 0, oa3 = 0, oa4 = 0, oa5 = 0;

#pragma unroll 2
      for (int r = 0; r < T_; ++r) {
        const int roff = r * C_;
        const unsigned* ta = (const unsigned*)(ft + base0 + roff);
        const unsigned* tb = (const unsigned*)(ft + base1 + roff);
        const unsigned* tc = (const unsigned*)(ft + base2 + roff);
        const unsigned* td = (const unsigned*)(ft + base3 + roff);
        unsigned ua0 = ta[0], ua1 = ta[1], ua2 = ta[2];
        unsigned ub0 = tb[0], ub1 = tb[1], ub2 = tb[2];
        unsigned uc0 = tc[0], uc1 = tc[1], uc2 = tc[2];
        unsigned ud0 = td[0], ud1 = td[1], ud2 = td[2];

        float s0 = tw0 * LOF(ua0) + tw1 * LOF(ub0) + tw2 * LOF(uc0) + tw3 * LOF(ud0);
        float s1 = tw0 * HIF(ua0) + tw1 * HIF(ub0) + tw2 * HIF(uc0) + tw3 * HIF(ud0);
        float s2 = tw0 * LOF(ua1) + tw1 * LOF(ub1) + tw2 * LOF(uc1) + tw3 * LOF(ud1);
        float s3 = tw0 * HIF(ua1) + tw1 * HIF(ub1) + tw2 * HIF(uc1) + tw3 * HIF(ud1);
        float s4 = tw0 * LOF(ua2) + tw1 * LOF(ub2) + tw2 * LOF(uc2) + tw3 * LOF(ud2);
        float s5 = tw0 * HIF(ua2) + tw1 * HIF(ub2) + tw2 * HIF(uc2) + tw3 * HIF(ud2);

        // logit: k-group reduce (lanes differing in bits 0..2 share p)
        float lg = q0 * s0 + q1 * s1 + q2 * s2 + q3 * s3 + q4 * s4 + q5 * s5;
        lg += __shfl_xor(lg, 1);
        lg += __shfl_xor(lg, 2);
        lg += __shfl_xor(lg, 4);
        lg *= 0.144337567297406441f;   // 1/sqrt(48)

        int dd = t - r; dd = dd < 0 ? -dd : dd;
        int npts = (56 - 8 * dd) / 7; npts = npts < 1 ? 1 : npts;
        if (p >= npts) lg = -1e30f;

        // softmax over p (lanes differing in bits 3..5 share k)
        float m = lg;
        m = fmaxf(m, __shfl_xor(m, 8));
        m = fmaxf(m, __shfl_xor(m, 16));
        m = fmaxf(m, __shfl_xor(m, 32));
        float e = __expf(lg - m);
        float ssum = e;
        ssum += __shfl_xor(ssum, 8);
        ssum += __shfl_xor(ssum, 16);
        ssum += __shfl_xor(ssum, 32);
        float attn = e / ssum * 0.125f;   // fold 1/T mean

        oa0 += attn * s0; oa1 += attn * s1; oa2 += attn * s2;
        oa3 += attn * s3; oa4 += attn * s4; oa5 += attn * s5;
      }

      // p-reduction (once per head)
      oa0 += __shfl_xor(oa0, 8); oa0 += __shfl_xor(oa0, 16); oa0 += __shfl_xor(oa0, 32);
      oa1 += __shfl_xor(oa1, 8); oa1 += __shfl_xor(oa1, 16); oa1 += __shfl_xor(oa1, 32);
      oa2 += __shfl_xor(oa2, 8); oa2 += __shfl_xor(oa2, 16); oa2 += __shfl_xor(oa2, 32);
      oa3 += __shfl_xor(oa3, 8); oa3 += __shfl_xor(oa3, 16); oa3 += __shfl_xor(oa3, 32);
      oa4 += __shfl_xor(oa4, 8); oa4 += __shfl_xor(oa4, 16); oa4 += __shfl_xor(oa4, 32);
      oa5 += __shfl_xor(oa5, 8); oa5 += __shfl_xor(oa5, 16); oa5 += __shfl_xor(oa5, 32);

      if (p == 0) {
        __hip_bfloat16* outp = O1 + row * C_ + h * HD_ + 6 * k;
        unsigned* u = (unsigned*)outp;          // 12B offset -> 4B aligned
        u[0] = (unsigned)bf16_bits(oa0) | ((unsigned)bf16_bits(oa1) << 16);
        u[1] = (unsigned)bf16_bits(oa2) | ((unsigned)bf16_bits(oa3) << 16);
        u[2] = (unsigned)bf16_bits(oa4) | ((unsigned)bf16_bits(oa5) << 16);
      }
    }
  }
}

// ---------------------------------------------------------------------------
extern "C" void kernel_launch(void* const* d_in, const int* in_sizes, int n_in,
                              void* d_out, int out_size, void* d_ws, size_t ws_size,
                              hipStream_t stream) {
  const float* f    = (const float*)d_in[0];
  const float* Wq   = (const float*)d_in[1];
  const float* bq   = (const float*)d_in[2];
  const float* Woff = (const float*)d_in[3];
  const float* boff = (const float*)d_in[4];
  const float* Wout = (const float*)d_in[5];
  const float* bout = (const float*)d_in[6];
  float* outp = (float*)d_out;

  // workspace layout (bytes):
  //   Qbuf  fp32 [M,384]   33.6 MB
  //   OFFb  fp32 [M,128]   11.2 MB
  //   ft    bf16 [B,N,T,C] 16.8 MB
  //   A16   bf16 [M,384]   16.8 MB   (aliased: O1 overwrites after GEMM1)
  //   Wt    bf16 [512,384]  0.4 MB
  //   Wot   bf16 [384,384]  0.3 MB
  float* Qbuf = (float*)d_ws;
  float* OFFb = Qbuf + (size_t)M_ * C_;
  __hip_bfloat16* ft  = (__hip_bfloat16*)(OFFb + (size_t)M_ * 128);
  __hip_bfloat16* A16 = ft + (size_t)B_ * N_ * T_ * C_;
  __hip_bfloat16* O1  = A16;   // alias: A16 dead after GEMM1, O1 written by attend
  __hip_bfloat16* Wt  = A16 + (size_t)M_ * C_;
  __hip_bfloat16* Wot = Wt + (size_t)512 * 384;

  dim3 blk(256);

  cast_a_kernel<<<dim3((M_ * C_) / 4 / 256), blk, 0, stream>>>(f, A16);
  prep_w_kernel<<<dim3(896), blk, 0, stream>>>(Wq, Woff, Wout, Wt, Wot);
  transpose_cast_kernel<<<dim3(B_ * N_), blk, 0, stream>>>(f, ft);

  // fused q+off GEMM: [M,384] @ [384,512] -> Qbuf / OFFb
  mfma_gemm_kernel<<<dim3((M_ + 127) / 128, 4), blk, 0, stream>>>(
      A16, Wt, bq, boff, Qbuf, OFFb, 1);

  attend_kernel<<<dim3(B_ * N_), blk, 0, stream>>>(ft, Qbuf, OFFb, O1);

  // output GEMM: [M,384] @ [384,384] -> outp
  mfma_gemm_kernel<<<dim3((M_ + 127) / 128, 3), blk, 0, stream>>>(
      O1, Wot, bout, nullptr, outp, nullptr, 0);
}

// Round 5
// 316.118 us; speedup vs baseline: 3.5190x; 1.2161x over previous
//
#include <hip/hip_runtime.h>
#include <hip/hip_bf16.h>
#include <cstddef>

// Problem constants
constexpr int B_  = 2;
constexpr int T_  = 8;
constexpr int HW_ = 37;          // H == W == 37
constexpr int N_  = HW_ * HW_;   // 1369
constexpr int C_  = 384;
constexpr int NH_ = 8;
constexpr int MP_ = 8;
constexpr int HD_ = C_ / NH_;    // 48
constexpr int M_  = B_ * T_ * N_; // 21904

typedef short bf16x8 __attribute__((ext_vector_type(8)));
typedef float f32x4 __attribute__((ext_vector_type(4)));
typedef float f32x2 __attribute__((ext_vector_type(2)));

static __device__ __forceinline__ unsigned short bf16_bits(float v) {
  __hip_bfloat16 b = __float2bfloat16(v);
  return *reinterpret_cast<unsigned short*>(&b);
}

static __device__ __forceinline__ f32x2 unpk(unsigned u) {
  f32x2 r;
  r.x = __uint_as_float(u << 16);
  r.y = __uint_as_float(u & 0xffff0000u);
  return r;
}

// ---------------------------------------------------------------------------
// cast f (fp32, [M*C]) -> A16 (bf16, same layout). 4 elems/thread.
// ---------------------------------------------------------------------------
__global__ __launch_bounds__(256)
void cast_a_kernel(const float* __restrict__ f, __hip_bfloat16* __restrict__ A16) {
  int i = blockIdx.x * 256 + threadIdx.x;
  float4 v = ((const float4*)f)[i];
  ushort4 o;
  o.x = bf16_bits(v.x); o.y = bf16_bits(v.y);
  o.z = bf16_bits(v.z); o.w = bf16_bits(v.w);
  ((ushort4*)A16)[i] = o;
}

// ---------------------------------------------------------------------------
// Pre-transpose weights to [N][K] bf16.
// ---------------------------------------------------------------------------
__global__ __launch_bounds__(256)
void prep_w_kernel(const float* __restrict__ Wq, const float* __restrict__ Woff,
                   const float* __restrict__ Wout,
                   __hip_bfloat16* __restrict__ Wt, __hip_bfloat16* __restrict__ Wot) {
  int nrow = blockIdx.x;           // 0..895
  if (nrow < 512) {
    const float* src; int col, ld;
    if (nrow < 384) { src = Wq; col = nrow; ld = 384; }
    else            { src = Woff; col = nrow - 384; ld = 128; }
    for (int k = threadIdx.x; k < 384; k += 256)
      Wt[(size_t)nrow * 384 + k] = __float2bfloat16(src[(size_t)k * ld + col]);
  } else {
    int col = nrow - 512;
    for (int k = threadIdx.x; k < 384; k += 256)
      Wot[(size_t)col * 384 + k] = __float2bfloat16(Wout[(size_t)k * 384 + col]);
  }
}

// ---------------------------------------------------------------------------
// Transpose + cast: ft[b][n][t][c] (bf16) = f[b][t][n][c] (fp32).
// ---------------------------------------------------------------------------
__global__ __launch_bounds__(256)
void transpose_cast_kernel(const float* __restrict__ f,
                           __hip_bfloat16* __restrict__ ft) {
  const int bn = blockIdx.x;
  const int n = bn % N_;
  const int b = bn / N_;
  const size_t dst_base = (size_t)bn * (T_ * C_);
#pragma unroll
  for (int i = 0; i < 12; ++i) {
    int idx = i * 256 + threadIdx.x;
    int t = idx / C_;
    int c = idx - t * C_;
    float v = f[((size_t)(b * T_ + t) * N_ + n) * C_ + c];
    ft[dst_base + idx] = __float2bfloat16(v);
  }
}

// ---------------------------------------------------------------------------
// bf16 MFMA GEMM: out[M,N] = (A[M,384] @ Wt[N,384]^T + bias) * out0_scale.
// split=1: N=512, cols<384 -> out0 (scaled), cols>=384 -> out1 (unscaled).
// ---------------------------------------------------------------------------
__global__ __launch_bounds__(256)
void mfma_gemm_kernel(const __hip_bfloat16* __restrict__ A,
                      const __hip_bfloat16* __restrict__ Wt,
                      const float* __restrict__ b0, const float* __restrict__ b1,
                      float* __restrict__ out0, float* __restrict__ out1,
                      int split, float out0_scale) {
  __shared__ __hip_bfloat16 As[128][40];
  __shared__ __hip_bfloat16 Bs[128][40];
  const int m0 = blockIdx.x * 128;
  const int n0 = blockIdx.y * 128;
  const int tid = threadIdx.x;
  const int wv = tid >> 6, lane = tid & 63;
  const int wr = wv >> 1, wc = wv & 1;
  const int lr = lane & 15, kg = lane >> 4;

  f32x4 acc[4][4] = {};

  for (int k0 = 0; k0 < 384; k0 += 32) {
#pragma unroll
    for (int u = 0; u < 2; ++u) {
      int c = tid + u * 256;
      int row = c >> 2;
      int off = (c & 3) * 8;
      int gm = m0 + row;
      uint4 va = make_uint4(0u, 0u, 0u, 0u);
      if (gm < M_) va = *(const uint4*)(A + (size_t)gm * 384 + k0 + off);
      *(uint4*)&As[row][off] = va;
      uint4 vb = *(const uint4*)(Wt + (size_t)(n0 + row) * 384 + k0 + off);
      *(uint4*)&Bs[row][off] = vb;
    }
    __syncthreads();

    bf16x8 af[4], bfr[4];
#pragma unroll
    for (int i = 0; i < 4; ++i)
      af[i] = *(const bf16x8*)&As[wr * 64 + i * 16 + lr][kg * 8];
#pragma unroll
    for (int i = 0; i < 4; ++i)
      bfr[i] = *(const bf16x8*)&Bs[wc * 64 + i * 16 + lr][kg * 8];

#pragma unroll
    for (int mi = 0; mi < 4; ++mi)
#pragma unroll
      for (int ni = 0; ni < 4; ++ni)
        acc[mi][ni] = __builtin_amdgcn_mfma_f32_16x16x32_bf16(
            af[mi], bfr[ni], acc[mi][ni], 0, 0, 0);
    __syncthreads();
  }

  const int mrow = (lane >> 4) * 4;
#pragma unroll
  for (int mi = 0; mi < 4; ++mi) {
#pragma unroll
    for (int ni = 0; ni < 4; ++ni) {
#pragma unroll
      for (int j = 0; j < 4; ++j) {
        int gm = m0 + wr * 64 + mi * 16 + mrow + j;
        int gn = n0 + wc * 64 + ni * 16 + lr;
        if (gm >= M_) continue;
        float v = acc[mi][ni][j];
        if (!split) {
          out0[(size_t)gm * 384 + gn] = (v + b0[gn]) * out0_scale;
        } else {
          if (gn < 384) out0[(size_t)gm * 384 + gn] = (v + b0[gn]) * out0_scale;
          else          out1[(size_t)gm * 128 + (gn - 384)] = v + b1[gn - 384];
        }
      }
    }
  }
}

// ---------------------------------------------------------------------------
// Deformable attention core.
// Grid = (bn, head-quad) = 5476 blocks (XCD-chunked bijective swizzle);
// 4 waves/block, ONE head per wave, t-loop inside (L2 reuse of ft).
// Lane role: p = lane>>3 (point), k = lane&7 (channel slice d = 6k..6k+5).
// Softmax without max-sub (logits O(1), masked -> e=0). Packed f32x2 math.
// 1/sqrt(48) folded into Q upstream; 1/T folded into final p-reduce.
// ---------------------------------------------------------------------------
__global__ __launch_bounds__(256)
void attend_kernel(const __hip_bfloat16* __restrict__ ft,
                   const float* __restrict__ Q,
                   const float* __restrict__ OFF,
                   __hip_bfloat16* __restrict__ O1) {
  // bijective chunked XCD swizzle over grid of B*N*2 = 5476 blocks
  const int grid = B_ * N_ * 2;
  const int q8 = grid / 8, r8 = grid % 8;
  int c = blockIdx.x & 7, j = blockIdx.x >> 3;
  int id = (c < r8) ? c * (q8 + 1) + j : r8 * (q8 + 1) + (c - r8) * q8 + j;
  const int hq = id & 1;
  const int bn = id >> 1;

  const int n = bn % N_;
  const int b = bn / N_;
  const int w    = threadIdx.x >> 6;
  const int h    = hq * 4 + w;          // one head per wave
  const int lane = threadIdx.x & 63;
  const int p = lane >> 3;
  const int k = lane & 7;
  const float cy = (float)(n / HW_);
  const float cx = (float)(n % HW_);
  const int bnb = b * N_;
  const int chb = h * HD_ + 6 * k;

  for (int t = 0; t < T_; ++t) {
    const size_t row = (size_t)(b * T_ + t) * N_ + n;

    // q fragment (pre-scaled by 1/sqrt(48) in GEMM epilogue)
    const f32x2* qp = (const f32x2*)(Q + row * C_ + h * HD_ + 6 * k);
    f32x2 q01 = qp[0], q23 = qp[1], q45 = qp[2];

    // bilinear taps for my point p
    const float* op = OFF + row * (NH_ * MP_ * 2) + h * (MP_ * 2) + p * 2;
    float y = cy + op[0];
    float x = cx + op[1];
    float y0f = floorf(y), x0f = floorf(x);
    float wy = y - y0f, wx = x - x0f;
    int y0 = (int)y0f, x0 = (int)x0f;
    int y1 = y0 + 1, x1 = x0 + 1;
    float vy0 = (y0 >= 0 && y0 < HW_) ? 1.f : 0.f;
    float vy1 = (y1 >= 0 && y1 < HW_) ? 1.f : 0.f;
    float vx0 = (x0 >= 0 && x0 < HW_) ? 1.f : 0.f;
    float vx1 = (x1 >= 0 && x1 < HW_) ? 1.f : 0.f;
    int cy0 = min(max(y0, 0), HW_ - 1), cy1 = min(max(y1, 0), HW_ - 1);
    int cx0 = min(max(x0, 0), HW_ - 1), cx1 = min(max(x1, 0), HW_ - 1);
    float tw0 = (1.f - wy) * (1.f - wx) * vy0 * vx0;
    float tw1 = (1.f - wy) * wx * vy0 * vx1;
    float tw2 = wy * (1.f - wx) * vy1 * vx0;
    float tw3 = wy * wx * vy1 * vx1;
    f32x2 tw0v = {tw0, tw0}, tw1v = {tw1, tw1}, tw2v = {tw2, tw2}, tw3v = {tw3, tw3};

    int base0 = ((bnb + cy0 * HW_ + cx0) * T_) * C_ + chb;
    int base1 = ((bnb + cy0 * HW_ + cx1) * T_) * C_ + chb;
    int base2 = ((bnb + cy1 * HW_ + cx0) * T_) * C_ + chb;
    int base3 = ((bnb + cy1 * HW_ + cx1) * T_) * C_ + chb;

    f32x2 oa01 = {0.f, 0.f}, oa23 = {0.f, 0.f}, oa45 = {0.f, 0.f};

#pragma unroll
    for (int r = 0; r < T_; ++r) {
      const int roff = r * C_;
      const unsigned* ta = (const unsigned*)(ft + base0 + roff);
      const unsigned* tb = (const unsigned*)(ft + base1 + roff);
      const unsigned* tc = (const unsigned*)(ft + base2 + roff);
      const unsigned* td = (const unsigned*)(ft + base3 + roff);
      unsigned ua0 = ta[0], ua1 = ta[1], ua2 = ta[2];
      unsigned ub0 = tb[0], ub1 = tb[1], ub2 = tb[2];
      unsigned uc0 = tc[0], uc1 = tc[1], uc2 = tc[2];
      unsigned ud0 = td[0], ud1 = td[1], ud2 = td[2];

      f32x2 s01 = unpk(ua0) * tw0v + unpk(ub0) * tw1v + unpk(uc0) * tw2v + unpk(ud0) * tw3v;
      f32x2 s23 = unpk(ua1) * tw0v + unpk(ub1) * tw1v + unpk(uc1) * tw2v + unpk(ud1) * tw3v;
      f32x2 s45 = unpk(ua2) * tw0v + unpk(ub2) * tw1v + unpk(uc2) * tw2v + unpk(ud2) * tw3v;

      // logit: packed dot + horizontal add, then k-group reduce (xor 1,2,4)
      f32x2 lg2 = q01 * s01 + q23 * s23 + q45 * s45;
      float lg = lg2.x + lg2.y;
      lg += __shfl_xor(lg, 1);
      lg += __shfl_xor(lg, 2);
      lg += __shfl_xor(lg, 4);

      // point-count mask for this (t, r)
      int dd = t - r; dd = dd < 0 ? -dd : dd;
      int npts = (56 - 8 * dd) / 7; npts = npts < 1 ? 1 : npts;

      // softmax over p without max-sub (logits O(1); masked -> 0)
      float e = (p < npts) ? __expf(lg) : 0.f;
      float ssum = e;
      ssum += __shfl_xor(ssum, 8);
      ssum += __shfl_xor(ssum, 16);
      ssum += __shfl_xor(ssum, 32);
      float attn = e * __builtin_amdgcn_rcpf(ssum);
      f32x2 attnv = {attn, attn};

      oa01 += attnv * s01;
      oa23 += attnv * s23;
      oa45 += attnv * s45;
    }

    // p-reduction (once per (t,h)), fold 1/T
    oa01.x += __shfl_xor(oa01.x, 8); oa01.x += __shfl_xor(oa01.x, 16); oa01.x += __shfl_xor(oa01.x, 32);
    oa01.y += __shfl_xor(oa01.y, 8); oa01.y += __shfl_xor(oa01.y, 16); oa01.y += __shfl_xor(oa01.y, 32);
    oa23.x += __shfl_xor(oa23.x, 8); oa23.x += __shfl_xor(oa23.x, 16); oa23.x += __shfl_xor(oa23.x, 32);
    oa23.y += __shfl_xor(oa23.y, 8); oa23.y += __shfl_xor(oa23.y, 16); oa23.y += __shfl_xor(oa23.y, 32);
    oa45.x += __shfl_xor(oa45.x, 8); oa45.x += __shfl_xor(oa45.x, 16); oa45.x += __shfl_xor(oa45.x, 32);
    oa45.y += __shfl_xor(oa45.y, 8); oa45.y += __shfl_xor(oa45.y, 16); oa45.y += __shfl_xor(oa45.y, 32);

    if (p == 0) {
      __hip_bfloat16* outp = O1 + row * C_ + h * HD_ + 6 * k;
      unsigned* u = (unsigned*)outp;
      u[0] = (unsigned)bf16_bits(oa01.x * 0.125f) | ((unsigned)bf16_bits(oa01.y * 0.125f) << 16);
      u[1] = (unsigned)bf16_bits(oa23.x * 0.125f) | ((unsigned)bf16_bits(oa23.y * 0.125f) << 16);
      u[2] = (unsigned)bf16_bits(oa45.x * 0.125f) | ((unsigned)bf16_bits(oa45.y * 0.125f) << 16);
    }
  }
}

// ---------------------------------------------------------------------------
extern "C" void kernel_launch(void* const* d_in, const int* in_sizes, int n_in,
                              void* d_out, int out_size, void* d_ws, size_t ws_size,
                              hipStream_t stream) {
  const float* f    = (const float*)d_in[0];
  const float* Wq   = (const float*)d_in[1];
  const float* bq   = (const float*)d_in[2];
  const float* Woff = (const float*)d_in[3];
  const float* boff = (const float*)d_in[4];
  const float* Wout = (const float*)d_in[5];
  const float* bout = (const float*)d_in[6];
  float* outp = (float*)d_out;

  float* Qbuf = (float*)d_ws;
  float* OFFb = Qbuf + (size_t)M_ * C_;
  __hip_bfloat16* ft  = (__hip_bfloat16*)(OFFb + (size_t)M_ * 128);
  __hip_bfloat16* A16 = ft + (size_t)B_ * N_ * T_ * C_;
  __hip_bfloat16* O1  = A16;   // alias: A16 dead after GEMM1, O1 written by attend
  __hip_bfloat16* Wt  = A16 + (size_t)M_ * C_;
  __hip_bfloat16* Wot = Wt + (size_t)512 * 384;

  dim3 blk(256);

  cast_a_kernel<<<dim3((M_ * C_) / 4 / 256), blk, 0, stream>>>(f, A16);
  prep_w_kernel<<<dim3(896), blk, 0, stream>>>(Wq, Woff, Wout, Wt, Wot);
  transpose_cast_kernel<<<dim3(B_ * N_), blk, 0, stream>>>(f, ft);

  // fused q+off GEMM: [M,384] @ [384,512] -> Qbuf (x 1/sqrt(48)) / OFFb
  mfma_gemm_kernel<<<dim3((M_ + 127) / 128, 4), blk, 0, stream>>>(
      A16, Wt, bq, boff, Qbuf, OFFb, 1, 0.144337567297406441f);

  attend_kernel<<<dim3(B_ * N_ * 2), blk, 0, stream>>>(ft, Qbuf, OFFb, O1);

  // output GEMM: [M,384] @ [384,384] -> outp
  mfma_gemm_kernel<<<dim3((M_ + 127) / 128, 3), blk, 0, stream>>>(
      O1, Wot, bout, nullptr, outp, nullptr, 0, 1.0f);
}